// Round 9
// baseline (618.780 us; speedup 1.0000x reference)
//
#include <hip/hip_runtime.h>
#include <math.h>

// B=8, Cin=256, H=W=128, RC=128, NC=12, HD=64, NL=3, E=132
#define BNS_F 0.9999950000374998f

typedef short short8 __attribute__((ext_vector_type(8)));   // 8 bf16 (4 VGPRs)
typedef float f32x4 __attribute__((ext_vector_type(4)));    // MFMA C/D frag

__device__ __forceinline__ unsigned short f2bf(float f) {
    unsigned u = __builtin_bit_cast(unsigned, f);
    unsigned r = (u + 0x7fffu + ((u >> 16) & 1u)) >> 16;   // RNE
    return (unsigned short)r;
}
__device__ __forceinline__ float bf2f(unsigned short h) {
    unsigned u = ((unsigned)h) << 16;
    return __builtin_bit_cast(float, u);
}

// =====================================================================
// prep: fused [convert_feat | reorg_w | masks]
//  blocks [0, 16384):        feat fp32 -> Fbt bf16 [b][ic/8][y][x][8ic]
//  blocks [16384, 16512):    W_rpn -> Wr[tap][oc][ic] bf16
//  blocks [16512, 22656):    maxpool masks + mask_sum (2 rows/block)
// =====================================================================
__global__ __launch_bounds__(256) void prep_kernel(
    const float* __restrict__ feat, unsigned short* __restrict__ Fbt,
    const float* __restrict__ Wrpn, unsigned short* __restrict__ Wr,
    const float* __restrict__ seg, float* __restrict__ masks,
    float* __restrict__ mask_sum)
{
    int bid = blockIdx.x;
    int t = threadIdx.x;

    if (bid < 16384) {
        int pxc = bid & 63;
        int icg = (bid >> 6) & 31;
        int b   = bid >> 11;
        int px  = pxc * 256 + t;
        const float* src = feat + ((size_t)(b * 256 + icg * 8)) * 16384 + px;
        unsigned v[4];
        #pragma unroll
        for (int i = 0; i < 4; ++i) {
            unsigned lo = f2bf(src[(size_t)(2 * i)     * 16384]);
            unsigned hi = f2bf(src[(size_t)(2 * i + 1) * 16384]);
            v[i] = lo | (hi << 16);
        }
        uint4 o; o.x = v[0]; o.y = v[1]; o.z = v[2]; o.w = v[3];
        *(uint4*)(Fbt + (((size_t)(b * 32 + icg) * 16384) + px) * 8) = o;
    } else if (bid < 16512) {
        int oc = bid - 16384;
        const float* src = Wrpn + ((size_t)oc * 256 + t) * 9;
        #pragma unroll
        for (int tap = 0; tap < 9; ++tap)
            Wr[((size_t)tap * 128 + oc) * 256 + t] = f2bf(src[tap]);
    } else {
        int mb = bid - 16512;                  // 0..6143
        int h = (mb & 63) * 2 + (t >> 7);
        int c = (mb >> 6) % 12;
        int b = mb / (64 * 12);
        int px = t & 127;

        const float* s = seg + ((size_t)(b * 12 + c) * 128) * 128;
        float m = -INFINITY;
        #pragma unroll
        for (int dy = -1; dy <= 1; ++dy) {
            int y = h + dy;
            if (y < 0 || y > 127) continue;
            #pragma unroll
            for (int dx = -1; dx <= 1; ++dx) {
                int x = px + dx;
                if (x < 0 || x > 127) continue;
                m = fmaxf(m, s[y * 128 + x]);
            }
        }
        float v = (m > 0.5f) ? 1.0f : 0.0f;
        masks[((size_t)(b * 12 + c) * 128 + h) * 128 + px] = v;

        float cnt = v;
        #pragma unroll
        for (int off = 1; off < 64; off <<= 1) cnt += __shfl_xor(cnt, off, 64);
        if ((t & 63) == 0) atomicAdd(&mask_sum[b * 12 + c], cnt);
    }
}

// =====================================================================
// MFMA implicit-GEMM conv + fused 1x1 + masked sums.  v7: barrier-free
// K-loop, B operands DIRECT from global (L1/L2) to MFMA registers.
// grid 1024 = B x H (XCD-swizzled), 256 thr = 4 waves, 4 blocks/CU
// (single generation). Wave = 64oc x 32px; block loops 2 px-halves.
// Halo: clamped address + per-lane zero-select (no padding, no stub).
// LDS only for the refined[128oc][64px] exchange before the fused 1x1.
// =====================================================================
#define CHUNK_STEP (4u * 16384u * 8u)   // +32 ic = +4 icg planes, in ushorts

__global__ __launch_bounds__(256, 4) void conv_node_kernel(
    const unsigned short* __restrict__ Fbt, const unsigned short* __restrict__ Wr,
    const float* __restrict__ brpn, const float* __restrict__ Wnode,
    const float* __restrict__ bnode, const float* __restrict__ masks,
    float* __restrict__ ms_rep)
{
    __shared__ unsigned short refined[128 * 66];   // 16.9 KB

    int wg = blockIdx.x;
    int bid = (wg & 7) * 128 + (wg >> 3);          // XCD x owns batch x
    int h = bid & 127, b = bid >> 7;

    int t = threadIdx.x;
    int lane = t & 63;
    int wv = __builtin_amdgcn_readfirstlane(t >> 6);  // 0..3
    int mg = wv >> 1;        // oc0 = mg*64
    int ng = wv & 1;         // px offset within half = ng*32
    int kg = lane >> 4;      // k-group 0..3
    int ln15 = lane & 15;

    // ---- y-clamped row bases (per-lane: kg selects icg plane) ----
    unsigned rowBase[3];
    bool ybad[3];
    #pragma unroll
    for (int dy = 0; dy < 3; ++dy) {
        int y = h - 1 + dy;
        int yc = y < 0 ? 0 : (y > 127 ? 127 : y);
        ybad[dy] = (y != yc);
        rowBase[dy] = ((unsigned)(b * 32 + kg) * 16384u + (unsigned)yc * 128u) * 8u;
    }

    int rep = bid & 7;
    float* msb = ms_rep + ((size_t)(rep * 8 + b) * 12) * 64 + wv * 16;
    const float* mrow = masks + ((size_t)b * 12 * 128 + h) * 128;

    for (int half = 0; half < 2; ++half) {
        // ---- x-clamped offsets + per-lane OOB flags, 6 = (nt,dxi) combos ----
        unsigned xo[6];
        bool xbad[6];
        #pragma unroll
        for (int nt = 0; nt < 2; ++nt)
            #pragma unroll
            for (int dxi = 0; dxi < 3; ++dxi) {
                int xr = half * 64 + ng * 32 + nt * 16 + ln15 + dxi - 1;
                int xc = xr < 0 ? 0 : (xr > 127 ? 127 : xr);
                xbad[nt * 3 + dxi] = (xr != xc);
                xo[nt * 3 + dxi] = (unsigned)xc * 8u;
            }

        f32x4 acc[4][2];
        #pragma unroll
        for (int f = 0; f < 4; ++f)
            #pragma unroll
            for (int nt = 0; nt < 2; ++nt) acc[f][nt] = (f32x4){0.f, 0.f, 0.f, 0.f};

        unsigned ri0 = rowBase[0], ri1 = rowBase[1], ri2 = rowBase[2];

        // ---- K-loop: NO barriers, NO LDS; loads straight to registers ----
        for (int s = 0; s < 8; ++s) {
            int ic0 = s * 32;
            #pragma unroll
            for (int dy = 0; dy < 3; ++dy) {
                unsigned rb = (dy == 0) ? ri0 : ((dy == 1) ? ri1 : ri2);
                bool yb = ybad[dy];
                #pragma unroll
                for (int dxi = 0; dxi < 3; ++dxi) {
                    int tap = dy * 3 + dxi;
                    const unsigned short* wp = Wr
                        + ((size_t)(tap * 128 + mg * 64 + ln15) * 256 + ic0 + kg * 8);
                    short8 a0 = *(const short8*)wp;
                    short8 a1 = *(const short8*)(wp + 16 * 256);
                    short8 a2 = *(const short8*)(wp + 32 * 256);
                    short8 a3 = *(const short8*)(wp + 48 * 256);

                    short8 b0 = *(const short8*)(Fbt + rb + xo[dxi]);
                    short8 b1 = *(const short8*)(Fbt + rb + xo[3 + dxi]);
                    if (yb | xbad[dxi])     b0 = (short8)0;
                    if (yb | xbad[3 + dxi]) b1 = (short8)0;

                    acc[0][0] = __builtin_amdgcn_mfma_f32_16x16x32_bf16(a0, b0, acc[0][0], 0, 0, 0);
                    acc[1][0] = __builtin_amdgcn_mfma_f32_16x16x32_bf16(a1, b0, acc[1][0], 0, 0, 0);
                    acc[2][0] = __builtin_amdgcn_mfma_f32_16x16x32_bf16(a2, b0, acc[2][0], 0, 0, 0);
                    acc[3][0] = __builtin_amdgcn_mfma_f32_16x16x32_bf16(a3, b0, acc[3][0], 0, 0, 0);
                    acc[0][1] = __builtin_amdgcn_mfma_f32_16x16x32_bf16(a0, b1, acc[0][1], 0, 0, 0);
                    acc[1][1] = __builtin_amdgcn_mfma_f32_16x16x32_bf16(a1, b1, acc[1][1], 0, 0, 0);
                    acc[2][1] = __builtin_amdgcn_mfma_f32_16x16x32_bf16(a2, b1, acc[2][1], 0, 0, 0);
                    acc[3][1] = __builtin_amdgcn_mfma_f32_16x16x32_bf16(a3, b1, acc[3][1], 0, 0, 0);
                }
            }
            ri0 += CHUNK_STEP; ri1 += CHUNK_STEP; ri2 += CHUNK_STEP;
        }

        // ---- epilogue: refined (bias/BNS/ReLU) -> LDS [128 oc][stride 66] ----
        #pragma unroll
        for (int f = 0; f < 4; ++f)
            #pragma unroll
            for (int nt = 0; nt < 2; ++nt)
                #pragma unroll
                for (int r = 0; r < 4; ++r) {
                    int oc = mg * 64 + f * 16 + kg * 4 + r;  // D: row=(lane>>4)*4+r
                    int pxl = ng * 32 + nt * 16 + ln15;
                    float v = fmaxf((acc[f][nt][r] + brpn[oc]) * BNS_F, 0.f);
                    refined[oc * 66 + pxl] = f2bf(v);
                }
        __syncthreads();

        // ---- fused 1x1: z[16 dims/wave] over 64 px (px = lane) ----
        float z[16];
        #pragma unroll
        for (int j = 0; j < 16; ++j) z[j] = 0.f;
        const float* wn = Wnode + (size_t)wv * 16 * 128;
        for (int k = 0; k < 128; ++k) {
            float rv = bf2f(refined[k * 66 + lane]);
            #pragma unroll
            for (int j = 0; j < 16; ++j)
                z[j] = fmaf(wn[j * 128 + k], rv, z[j]);
        }
        #pragma unroll
        for (int j = 0; j < 16; ++j)
            z[j] = fmaxf((z[j] + bnode[wv * 16 + j]) * BNS_F, 0.f);

        // ---- masked accumulation into replica rep ----
        #pragma unroll 2
        for (int c = 0; c < 12; ++c) {
            float m = mrow[(size_t)c * 16384 + half * 64 + lane];
            #pragma unroll
            for (int j = 0; j < 16; ++j) {
                float v = z[j] * m;
                #pragma unroll
                for (int off = 1; off < 64; off <<= 1) v += __shfl_xor(v, off, 64);
                if (lane == j) atomicAdd(&msb[c * 64 + j], v);
            }
        }
        __syncthreads();   // refined reused by next half
    }
}

// =====================================================================
// edge MLP: 264 blocks = 8 b x 33 edge-groups; wave = one edge
// =====================================================================
__global__ __launch_bounds__(256) void edge_kernel(
    const float* __restrict__ ms_rep, const float* __restrict__ mask_sum,
    const float* __restrict__ We1, const float* __restrict__ be1,
    const float* __restrict__ We2, const float* __restrict__ be2,
    float* __restrict__ ea_g)
{
    int gb = blockIdx.x;
    int b = gb / 33, eg = gb % 33;
    int wv = threadIdx.x >> 6, d = threadIdx.x & 63;
    int e = eg * 4 + wv;                    // 0..131
    int src = e / 11, jj = e % 11;
    int dst = jj + (jj >= src ? 1 : 0);

    float mssrc = 0.f, msdst = 0.f;
    #pragma unroll
    for (int rep = 0; rep < 8; ++rep) {
        mssrc += ms_rep[((size_t)(rep * 8 + b) * 12 + src) * 64 + d];
        msdst += ms_rep[((size_t)(rep * 8 + b) * 12 + dst) * 64 + d];
    }
    float cs = mask_sum[b * 12 + src], cd = mask_sum[b * 12 + dst];
    float nsrc = mssrc / (cs + 1e-6f);
    float ndst = msdst / (cd + 1e-6f);

    float hv = be1[d];
    for (int k = 0; k < 64; ++k) hv = fmaf(__shfl(nsrc, k, 64), We1[k * 64 + d], hv);
    for (int k = 0; k < 64; ++k) hv = fmaf(__shfl(ndst, k, 64), We1[(64 + k) * 64 + d], hv);
    hv = fmaxf(hv, 0.f);
    float av = be2[d];
    for (int k = 0; k < 64; ++k) av = fmaf(__shfl(hv, k, 64), We2[k * 64 + d], av);

    float valid = ((cs > 0.f) ? 1.f : 0.f) * ((cd > 0.f) ? 1.f : 0.f);
    ea_g[((size_t)b * 132 + e) * 64 + d] = av * valid;
}

// =====================================================================
// graph: node_feats -> 3-layer GNN -> xs = x_final @ W_sp  (8 blocks)
// =====================================================================
__global__ __launch_bounds__(256) void graph_kernel(
    const float* __restrict__ ms_rep, const float* __restrict__ mask_sum,
    const float* __restrict__ ea_g,
    const float* __restrict__ Wg, const float* __restrict__ bg,
    const float* __restrict__ lng, const float* __restrict__ lnb,
    const float* __restrict__ glob, const float* __restrict__ Wsp,
    float* __restrict__ xs_out)
{
    __shared__ float nf[12 * 64];
    __shared__ float x [12 * 64];
    __shared__ float xw[12 * 64];
    __shared__ float ea[132 * 64];
    __shared__ float presence[12];

    int b = blockIdx.x;
    int t = threadIdx.x;

    for (int i = t; i < 768; i += 256) {
        int c = i >> 6, d = i & 63;
        float ms = 0.f;
        #pragma unroll
        for (int rep = 0; rep < 8; ++rep)
            ms += ms_rep[((size_t)(rep * 8 + b) * 12 + c) * 64 + d];
        nf[i] = ms / (mask_sum[b * 12 + c] + 1e-6f);
    }
    for (int i = t; i < 132 * 64; i += 256) ea[i] = ea_g[(size_t)b * 8448 + i];
    __syncthreads();

    for (int i = t; i < 768; i += 256) {
        int c = i >> 6;
        float v = nf[i];
        #pragma unroll
        for (int off = 1; off < 64; off <<= 1) v += __shfl_xor(v, off, 64);
        if ((i & 63) == 0) presence[c] = (v != 0.f) ? 1.f : 0.f;
        x[i] = nf[i];
    }
    __syncthreads();

    for (int l = 0; l < 3; ++l) {
        const float* wg = Wg + l * 4096;
        for (int i = t; i < 768; i += 256) {
            int c = i >> 6, d = i & 63;
            float v = 0.f;
            for (int k = 0; k < 64; ++k) v = fmaf(x[c * 64 + k], wg[k * 64 + d], v);
            xw[i] = v;
        }
        __syncthreads();
        for (int i = t; i < 768; i += 256) {
            int j = i >> 6, d = i & 63;
            float agg = bg[l * 64 + d];
            #pragma unroll
            for (int src2 = 0; src2 < 12; ++src2) {
                if (src2 == j) continue;
                int jj2 = j - (j > src2 ? 1 : 0);
                int e = src2 * 11 + jj2;
                agg = fmaf(xw[src2 * 64 + d], ea[e * 64 + d], agg);
            }
            float xr = fmaxf(agg, 0.f);
            float s = xr;
            #pragma unroll
            for (int off = 1; off < 64; off <<= 1) s += __shfl_xor(s, off, 64);
            float mu = s * (1.f / 64.f);
            float df = xr - mu;
            float s2 = df * df;
            #pragma unroll
            for (int off = 1; off < 64; off <<= 1) s2 += __shfl_xor(s2, off, 64);
            float var = s2 * (1.f / 64.f);
            float normed = df * (1.0f / sqrtf(var + 1e-5f)) * lng[l * 64 + d]
                           + lnb[l * 64 + d];
            nf[i] = (l > 0) ? (normed + x[i]) : normed;
        }
        __syncthreads();
        for (int i = t; i < 768; i += 256) x[i] = nf[i];
        __syncthreads();
    }

    for (int i = t; i < 768; i += 256) {
        int c = i >> 6;
        float p = presence[c];
        x[i] = x[i] * p + glob[c * 64 + (i & 63)] * (1.f - p);
    }
    __syncthreads();

    for (int i = t; i < 12 * 128; i += 256) {
        int c = i >> 7, o = i & 127;
        float v = 0.f;
        for (int k = 0; k < 64; ++k) v = fmaf(x[c * 64 + k], Wsp[k * 128 + o], v);
        xs_out[b * 1536 + i] = v;
    }
}

// =====================================================================
// out[b,o,h,w] = relu((sum_c xs[b,c,o]*mask[b,c,h,w] + b_sp[o])*BNS)
// =====================================================================
__global__ __launch_bounds__(256) void out_kernel(
    const float* __restrict__ xs, const float* __restrict__ masks,
    const float* __restrict__ bsp, float* __restrict__ out)
{
    __shared__ float xsl[12 * 128];
    __shared__ float ml[12 * 128];
    int bid = blockIdx.x;
    int h = bid & 127;
    int b = bid >> 7;
    int t = threadIdx.x;

    for (int i = t; i < 1536; i += 256) xsl[i] = xs[b * 1536 + i];
    for (int i = t; i < 1536; i += 256) {
        int c = i >> 7, px = i & 127;
        ml[i] = masks[((size_t)(b * 12 + c) * 128 + h) * 128 + px];
    }
    __syncthreads();

    int px = t & 127;
    int og = t >> 7;
    float m[12];
    #pragma unroll
    for (int c = 0; c < 12; ++c) m[c] = ml[c * 128 + px];

    float* ob = out + ((size_t)b * 128 * 128 + h) * 128 + px;
    for (int i = 0; i < 64; ++i) {
        int o = og * 64 + i;
        float s = 0.f;
        #pragma unroll
        for (int c = 0; c < 12; ++c) s = fmaf(xsl[c * 128 + o], m[c], s);
        ob[(size_t)o * 16384] = fmaxf((s + bsp[o]) * BNS_F, 0.f);
    }
}

// =====================================================================
extern "C" void kernel_launch(void* const* d_in, const int* in_sizes, int n_in,
                              void* d_out, int out_size, void* d_ws, size_t ws_size,
                              hipStream_t stream)
{
    const float* feat  = (const float*)d_in[0];
    const float* seg   = (const float*)d_in[1];
    const float* Wrpn  = (const float*)d_in[2];
    const float* brpn  = (const float*)d_in[3];
    const float* Wnode = (const float*)d_in[4];
    const float* bnode = (const float*)d_in[5];
    const float* We1   = (const float*)d_in[6];
    const float* be1   = (const float*)d_in[7];
    const float* We2   = (const float*)d_in[8];
    const float* be2   = (const float*)d_in[9];
    const float* Wg    = (const float*)d_in[10];
    const float* bg    = (const float*)d_in[11];
    const float* lng   = (const float*)d_in[12];
    const float* lnb   = (const float*)d_in[13];
    const float* glob  = (const float*)d_in[14];
    const float* Wsp   = (const float*)d_in[15];
    const float* bsp   = (const float*)d_in[16];
    float* out = (float*)d_out;

    // Fbt (bf16 features, grouped pixel-major) lives in d_out (67.1 MB);
    // fully consumed by conv before out_kernel overwrites it.
    unsigned short* Fbt = (unsigned short*)d_out;

    // workspace (floats):
    float* masks    = (float*)d_ws;              // 1,572,864
    float* ms_rep   = masks + 1572864;           // 8*8*12*64 = 49,152
    float* mask_sum = ms_rep + 49152;            // 96
    float* xs       = mask_sum + 96;             // 12,288
    float* ea_g     = xs + 12288;                // 8*132*64 = 67,584
    unsigned short* Wr = (unsigned short*)(ea_g + 67584);  // 294,912 bf16

    hipMemsetAsync(ms_rep, 0, (49152 + 96) * sizeof(float), stream);

    prep_kernel<<<22656, 256, 0, stream>>>(feat, Fbt, Wrpn, Wr, seg, masks, mask_sum);
    conv_node_kernel<<<1024, 256, 0, stream>>>(Fbt, Wr, brpn, Wnode, bnode,
                                               masks, ms_rep);
    edge_kernel<<<264, 256, 0, stream>>>(ms_rep, mask_sum, We1, be1, We2, be2, ea_g);
    graph_kernel<<<8, 256, 0, stream>>>(ms_rep, mask_sum, ea_g,
                                        Wg, bg, lng, lnb, glob, Wsp, xs);
    out_kernel<<<1024, 256, 0, stream>>>(xs, masks, bsp, out);
}

// Round 10
// 566.188 us; speedup vs baseline: 1.0929x; 1.0929x over previous
//
#include <hip/hip_runtime.h>
#include <math.h>

// B=8, Cin=256, H=W=128, RC=128, NC=12, HD=64, NL=3, E=132
#define BNS_F 0.9999950000374998f

typedef short short8 __attribute__((ext_vector_type(8)));    // 8 bf16 (4 VGPRs)
typedef float f32x16 __attribute__((ext_vector_type(16)));   // 32x32 MFMA C/D frag

typedef __attribute__((address_space(3))) void lds_void;
typedef const __attribute__((address_space(1))) void glb_void;

__device__ __forceinline__ unsigned short f2bf(float f) {
    unsigned u = __builtin_bit_cast(unsigned, f);
    unsigned r = (u + 0x7fffu + ((u >> 16) & 1u)) >> 16;   // RNE
    return (unsigned short)r;
}
__device__ __forceinline__ float bf2f(unsigned short h) {
    unsigned u = ((unsigned)h) << 16;
    return __builtin_bit_cast(float, u);
}

// =====================================================================
// prep: fused [convert_feat | reorg_w | masks]
//  blocks [0, 16384):        feat fp32 -> Fbt bf16 [b][ic/8][y][x][8ic]
//  blocks [16384, 16512):    W_rpn -> Wr[tap][oc][ic] bf16
//  blocks [16512, 22656):    maxpool masks + mask_sum (2 rows/block)
// =====================================================================
__global__ __launch_bounds__(256) void prep_kernel(
    const float* __restrict__ feat, unsigned short* __restrict__ Fbt,
    const float* __restrict__ Wrpn, unsigned short* __restrict__ Wr,
    const float* __restrict__ seg, float* __restrict__ masks,
    float* __restrict__ mask_sum)
{
    int bid = blockIdx.x;
    int t = threadIdx.x;

    if (bid < 16384) {
        int pxc = bid & 63;
        int icg = (bid >> 6) & 31;
        int b   = bid >> 11;
        int px  = pxc * 256 + t;
        const float* src = feat + ((size_t)(b * 256 + icg * 8)) * 16384 + px;
        unsigned v[4];
        #pragma unroll
        for (int i = 0; i < 4; ++i) {
            unsigned lo = f2bf(src[(size_t)(2 * i)     * 16384]);
            unsigned hi = f2bf(src[(size_t)(2 * i + 1) * 16384]);
            v[i] = lo | (hi << 16);
        }
        uint4 o; o.x = v[0]; o.y = v[1]; o.z = v[2]; o.w = v[3];
        *(uint4*)(Fbt + (((size_t)(b * 32 + icg) * 16384) + px) * 8) = o;
    } else if (bid < 16512) {
        int oc = bid - 16384;
        const float* src = Wrpn + ((size_t)oc * 256 + t) * 9;
        #pragma unroll
        for (int tap = 0; tap < 9; ++tap)
            Wr[((size_t)tap * 128 + oc) * 256 + t] = f2bf(src[tap]);
    } else {
        int mb = bid - 16512;                  // 0..6143
        int h = (mb & 63) * 2 + (t >> 7);
        int c = (mb >> 6) % 12;
        int b = mb / (64 * 12);
        int px = t & 127;

        const float* s = seg + ((size_t)(b * 12 + c) * 128) * 128;
        float m = -INFINITY;
        #pragma unroll
        for (int dy = -1; dy <= 1; ++dy) {
            int y = h + dy;
            if (y < 0 || y > 127) continue;
            #pragma unroll
            for (int dx = -1; dx <= 1; ++dx) {
                int x = px + dx;
                if (x < 0 || x > 127) continue;
                m = fmaxf(m, s[y * 128 + x]);
            }
        }
        float v = (m > 0.5f) ? 1.0f : 0.0f;
        masks[((size_t)(b * 12 + c) * 128 + h) * 128 + px] = v;

        float cnt = v;
        #pragma unroll
        for (int off = 1; off < 64; off <<= 1) cnt += __shfl_xor(cnt, off, 64);
        if ((t & 63) == 0) atomicAdd(&mask_sum[b * 12 + c], cnt);
    }
}

// =====================================================================
// MFMA implicit-GEMM conv + fused 1x1 + masked sums.  v8: R6 skeleton
// (best measured 247us) with 32x32x16 MFMA: half the MFMA instructions,
// half the ds_reads per FLOP, and slot-major LDS layout [row][slot][col]
// (chunk offset stays linear c*16; B-read banks 2-way max, no swizzle).
// grid 1024 = B x H (XCD-swizzled), 512 thr = 8 waves.
// Wave (mw,nw): 64 oc x 32 px; per kstep-tap: 2 A(global) + 1 B(lds)
// + 2 MFMA(8cyc). Stage-after-compute (R6 order), plain __syncthreads.
// =====================================================================
#define BUF_BYTES 24960                  // 1560 chunks * 16B
#define CHUNK_STEP (4u * 16384u * 8u)    // +32 ic = +4 icg planes, ushorts

__global__ __launch_bounds__(512) void conv_node_kernel(
    const unsigned short* __restrict__ Fbt, const unsigned short* __restrict__ Wr,
    const float* __restrict__ brpn, const float* __restrict__ Wnode,
    const float* __restrict__ bnode, const float* __restrict__ masks,
    const float* __restrict__ zero16, float* __restrict__ ms_rep)
{
    __shared__ __align__(16) unsigned char lds[49920];  // dbuf staging; epilogue reuses

    // XCD swizzle: 1024 wgs, XCD x gets logical blocks [x*128, x*128+128) = batch x
    int wg = blockIdx.x;
    int bid = (wg & 7) * 128 + (wg >> 3);
    int h = bid & 127, b = bid >> 7;

    int t = threadIdx.x;
    int lane = t & 63;
    int wv = __builtin_amdgcn_readfirstlane(t >> 6);  // 0..7 wave-uniform
    int mw = wv >> 2;          // oc0 = mw*64
    int nw = wv & 3;           // px0 = nw*32
    int ln31 = lane & 31;
    int khalf = lane >> 5;     // 0,1
    int px0 = nw * 32;

    f32x16 acc0 = (f32x16)0.f, acc1 = (f32x16)0.f;

    const unsigned short* zp = (const unsigned short*)zero16;

    // ---- per-thread staging pointers, computed ONCE ----
    // buffer layout: [row 0..2][slot 0..3][col 0..129] x16B; chunk c -> off c*16
    // c = row*520 + slot*130 + col
    const unsigned short* pp[4];
    unsigned inc[4];
    #pragma unroll
    for (int r = 0; r < 4; ++r) {
        int c = (r < 3) ? (r * 512 + t) : (1536 + t);
        bool act = (r < 3) || (t < 24);
        int row = c / 520;
        int rem = c - row * 520;
        int slot = rem / 130;
        int col = rem - slot * 130;
        int y = h - 1 + row, x = col - 1;
        bool in = act && ((unsigned)y < 128u) && ((unsigned)x < 128u);
        pp[r] = in ? (Fbt + (((size_t)(b * 32 + slot) * 16384) + y * 128 + x) * 8)
                   : zp;
        inc[r] = in ? CHUNK_STEP : 0u;
    }

    auto stage = [&](int bsel) {
        #pragma unroll
        for (int r = 0; r < 3; ++r) {
            unsigned ldsoff = (unsigned)bsel * BUF_BYTES
                            + (unsigned)(r * 512 + wv * 64) * 16;
            __builtin_amdgcn_global_load_lds((glb_void*)pp[r],
                (lds_void*)(lds + ldsoff), 16, 0, 0);
            pp[r] += inc[r];
        }
        if (t < 24) {
            unsigned ldsoff = (unsigned)bsel * BUF_BYTES + 1536u * 16;
            __builtin_amdgcn_global_load_lds((glb_void*)pp[3],
                (lds_void*)(lds + ldsoff), 16, 0, 0);
        }
        pp[3] += inc[3];
    };

    stage(0);
    __syncthreads();

    for (int s = 0; s < 8; ++s) {
        int ic0 = s * 32;
        const unsigned char* buf = lds + (s & 1) * BUF_BYTES;

        // ---- compute chunk s: 2 ksteps x 9 taps x (2A + 1B + 2 MFMA) ----
        #pragma unroll
        for (int ks = 0; ks < 2; ++ks) {
            #pragma unroll
            for (int dy = 0; dy < 3; ++dy) {
                #pragma unroll
                for (int dxi = 0; dxi < 3; ++dxi) {
                    int tap = dy * 3 + dxi;
                    const unsigned short* wp = Wr
                        + ((size_t)(tap * 128 + mw * 64 + ln31) * 256
                           + ic0 + ks * 16 + khalf * 8);
                    short8 a0 = *(const short8*)wp;
                    short8 a1 = *(const short8*)(wp + 32 * 256);

                    unsigned off = (unsigned)dy * 8320u
                                 + (unsigned)(2 * ks + khalf) * 2080u
                                 + (unsigned)(px0 + ln31 + dxi) * 16u;
                    short8 bf = *(const short8*)(buf + off);

                    acc0 = __builtin_amdgcn_mfma_f32_32x32x16_bf16(
                        a0, bf, acc0, 0, 0, 0);
                    acc1 = __builtin_amdgcn_mfma_f32_32x32x16_bf16(
                        a1, bf, acc1, 0, 0, 0);
                }
            }
        }

        // ---- prefetch next chunk AFTER compute-issue (R6 proven order) ----
        if (s < 7) stage((s + 1) & 1);
        __syncthreads();
    }

    // ---- epilogue: refined (bias/BNS/ReLU) -> LDS bf16 [128 oc][stride 130] ----
    // D (32x32): col = lane&31 -> px; row = (reg&3) + 8*(reg>>2) + 4*(lane>>5)
    unsigned short* refined = (unsigned short*)lds;
    int px = px0 + ln31;
    #pragma unroll
    for (int reg = 0; reg < 16; ++reg) {
        int row = (reg & 3) + 8 * (reg >> 2) + 4 * khalf;
        int oc0 = mw * 64 + row;
        float v0 = fmaxf((acc0[reg] + brpn[oc0]) * BNS_F, 0.f);
        refined[oc0 * 130 + px] = f2bf(v0);
        int oc1 = oc0 + 32;
        float v1 = fmaxf((acc1[reg] + brpn[oc1]) * BNS_F, 0.f);
        refined[oc1 * 130 + px] = f2bf(v1);
    }
    __syncthreads();

    // ---- phase 2: z = relu((W_node @ refined + b)*BNS); wave -> 8 dims ----
    float z0[8], z1[8];
    #pragma unroll
    for (int j = 0; j < 8; ++j) { z0[j] = 0.f; z1[j] = 0.f; }
    const float* wn = Wnode + (size_t)wv * 8 * 128;
    for (int k = 0; k < 128; ++k) {
        float r0 = bf2f(refined[k * 130 + lane]);
        float r1 = bf2f(refined[k * 130 + 64 + lane]);
        #pragma unroll
        for (int j = 0; j < 8; ++j) {
            float w = wn[j * 128 + k];
            z0[j] = fmaf(w, r0, z0[j]);
            z1[j] = fmaf(w, r1, z1[j]);
        }
    }
    #pragma unroll
    for (int j = 0; j < 8; ++j) {
        float bb = bnode[wv * 8 + j];
        z0[j] = fmaxf((z0[j] + bb) * BNS_F, 0.f);
        z1[j] = fmaxf((z1[j] + bb) * BNS_F, 0.f);
    }

    // ---- masked accumulation into replica rep = bid&7 ----
    int rep = bid & 7;
    const float* mrow = masks + ((size_t)b * 12 * 128 + h) * 128;
    float* msb = ms_rep + ((size_t)(rep * 8 + b) * 12) * 64 + wv * 8;
    for (int c = 0; c < 12; ++c) {
        float m0 = mrow[(size_t)c * 16384 + lane];
        float m1 = mrow[(size_t)c * 16384 + 64 + lane];
        #pragma unroll
        for (int j = 0; j < 8; ++j) {
            float v = fmaf(z0[j], m0, z1[j] * m1);
            #pragma unroll
            for (int off2 = 1; off2 < 64; off2 <<= 1) v += __shfl_xor(v, off2, 64);
            if (lane == 0) atomicAdd(&msb[c * 64 + j], v);
        }
    }
}

// =====================================================================
// edge MLP: 264 blocks = 8 b x 33 edge-groups; wave = one edge
// =====================================================================
__global__ __launch_bounds__(256) void edge_kernel(
    const float* __restrict__ ms_rep, const float* __restrict__ mask_sum,
    const float* __restrict__ We1, const float* __restrict__ be1,
    const float* __restrict__ We2, const float* __restrict__ be2,
    float* __restrict__ ea_g)
{
    int gb = blockIdx.x;
    int b = gb / 33, eg = gb % 33;
    int wv = threadIdx.x >> 6, d = threadIdx.x & 63;
    int e = eg * 4 + wv;                    // 0..131
    int src = e / 11, jj = e % 11;
    int dst = jj + (jj >= src ? 1 : 0);

    float mssrc = 0.f, msdst = 0.f;
    #pragma unroll
    for (int rep = 0; rep < 8; ++rep) {
        mssrc += ms_rep[((size_t)(rep * 8 + b) * 12 + src) * 64 + d];
        msdst += ms_rep[((size_t)(rep * 8 + b) * 12 + dst) * 64 + d];
    }
    float cs = mask_sum[b * 12 + src], cd = mask_sum[b * 12 + dst];
    float nsrc = mssrc / (cs + 1e-6f);
    float ndst = msdst / (cd + 1e-6f);

    float hv = be1[d];
    for (int k = 0; k < 64; ++k) hv = fmaf(__shfl(nsrc, k, 64), We1[k * 64 + d], hv);
    for (int k = 0; k < 64; ++k) hv = fmaf(__shfl(ndst, k, 64), We1[(64 + k) * 64 + d], hv);
    hv = fmaxf(hv, 0.f);
    float av = be2[d];
    for (int k = 0; k < 64; ++k) av = fmaf(__shfl(hv, k, 64), We2[k * 64 + d], av);

    float valid = ((cs > 0.f) ? 1.f : 0.f) * ((cd > 0.f) ? 1.f : 0.f);
    ea_g[((size_t)b * 132 + e) * 64 + d] = av * valid;
}

// =====================================================================
// graph: node_feats -> 3-layer GNN -> xs = x_final @ W_sp  (8 blocks)
// =====================================================================
__global__ __launch_bounds__(256) void graph_kernel(
    const float* __restrict__ ms_rep, const float* __restrict__ mask_sum,
    const float* __restrict__ ea_g,
    const float* __restrict__ Wg, const float* __restrict__ bg,
    const float* __restrict__ lng, const float* __restrict__ lnb,
    const float* __restrict__ glob, const float* __restrict__ Wsp,
    float* __restrict__ xs_out)
{
    __shared__ float nf[12 * 64];
    __shared__ float x [12 * 64];
    __shared__ float xw[12 * 64];
    __shared__ float ea[132 * 64];
    __shared__ float presence[12];

    int b = blockIdx.x;
    int t = threadIdx.x;

    for (int i = t; i < 768; i += 256) {
        int c = i >> 6, d = i & 63;
        float ms = 0.f;
        #pragma unroll
        for (int rep = 0; rep < 8; ++rep)
            ms += ms_rep[((size_t)(rep * 8 + b) * 12 + c) * 64 + d];
        nf[i] = ms / (mask_sum[b * 12 + c] + 1e-6f);
    }
    for (int i = t; i < 132 * 64; i += 256) ea[i] = ea_g[(size_t)b * 8448 + i];
    __syncthreads();

    for (int i = t; i < 768; i += 256) {
        int c = i >> 6;
        float v = nf[i];
        #pragma unroll
        for (int off = 1; off < 64; off <<= 1) v += __shfl_xor(v, off, 64);
        if ((i & 63) == 0) presence[c] = (v != 0.f) ? 1.f : 0.f;
        x[i] = nf[i];
    }
    __syncthreads();

    for (int l = 0; l < 3; ++l) {
        const float* wg = Wg + l * 4096;
        for (int i = t; i < 768; i += 256) {
            int c = i >> 6, d = i & 63;
            float v = 0.f;
            for (int k = 0; k < 64; ++k) v = fmaf(x[c * 64 + k], wg[k * 64 + d], v);
            xw[i] = v;
        }
        __syncthreads();
        for (int i = t; i < 768; i += 256) {
            int j = i >> 6, d = i & 63;
            float agg = bg[l * 64 + d];
            #pragma unroll
            for (int src2 = 0; src2 < 12; ++src2) {
                if (src2 == j) continue;
                int jj2 = j - (j > src2 ? 1 : 0);
                int e = src2 * 11 + jj2;
                agg = fmaf(xw[src2 * 64 + d], ea[e * 64 + d], agg);
            }
            float xr = fmaxf(agg, 0.f);
            float s = xr;
            #pragma unroll
            for (int off = 1; off < 64; off <<= 1) s += __shfl_xor(s, off, 64);
            float mu = s * (1.f / 64.f);
            float df = xr - mu;
            float s2 = df * df;
            #pragma unroll
            for (int off = 1; off < 64; off <<= 1) s2 += __shfl_xor(s2, off, 64);
            float var = s2 * (1.f / 64.f);
            float normed = df * (1.0f / sqrtf(var + 1e-5f)) * lng[l * 64 + d]
                           + lnb[l * 64 + d];
            nf[i] = (l > 0) ? (normed + x[i]) : normed;
        }
        __syncthreads();
        for (int i = t; i < 768; i += 256) x[i] = nf[i];
        __syncthreads();
    }

    for (int i = t; i < 768; i += 256) {
        int c = i >> 6;
        float p = presence[c];
        x[i] = x[i] * p + glob[c * 64 + (i & 63)] * (1.f - p);
    }
    __syncthreads();

    for (int i = t; i < 12 * 128; i += 256) {
        int c = i >> 7, o = i & 127;
        float v = 0.f;
        for (int k = 0; k < 64; ++k) v = fmaf(x[c * 64 + k], Wsp[k * 128 + o], v);
        xs_out[b * 1536 + i] = v;
    }
}

// =====================================================================
// out[b,o,h,w] = relu((sum_c xs[b,c,o]*mask[b,c,h,w] + b_sp[o])*BNS)
// =====================================================================
__global__ __launch_bounds__(256) void out_kernel(
    const float* __restrict__ xs, const float* __restrict__ masks,
    const float* __restrict__ bsp, float* __restrict__ out)
{
    __shared__ float xsl[12 * 128];
    __shared__ float ml[12 * 128];
    int bid = blockIdx.x;
    int h = bid & 127;
    int b = bid >> 7;
    int t = threadIdx.x;

    for (int i = t; i < 1536; i += 256) xsl[i] = xs[b * 1536 + i];
    for (int i = t; i < 1536; i += 256) {
        int c = i >> 7, px = i & 127;
        ml[i] = masks[((size_t)(b * 12 + c) * 128 + h) * 128 + px];
    }
    __syncthreads();

    int px = t & 127;
    int og = t >> 7;
    float m[12];
    #pragma unroll
    for (int c = 0; c < 12; ++c) m[c] = ml[c * 128 + px];

    float* ob = out + ((size_t)b * 128 * 128 + h) * 128 + px;
    for (int i = 0; i < 64; ++i) {
        int o = og * 64 + i;
        float s = 0.f;
        #pragma unroll
        for (int c = 0; c < 12; ++c) s = fmaf(xsl[c * 128 + o], m[c], s);
        ob[(size_t)o * 16384] = fmaxf((s + bsp[o]) * BNS_F, 0.f);
    }
}

// =====================================================================
extern "C" void kernel_launch(void* const* d_in, const int* in_sizes, int n_in,
                              void* d_out, int out_size, void* d_ws, size_t ws_size,
                              hipStream_t stream)
{
    const float* feat  = (const float*)d_in[0];
    const float* seg   = (const float*)d_in[1];
    const float* Wrpn  = (const float*)d_in[2];
    const float* brpn  = (const float*)d_in[3];
    const float* Wnode = (const float*)d_in[4];
    const float* bnode = (const float*)d_in[5];
    const float* We1   = (const float*)d_in[6];
    const float* be1   = (const float*)d_in[7];
    const float* We2   = (const float*)d_in[8];
    const float* be2   = (const float*)d_in[9];
    const float* Wg    = (const float*)d_in[10];
    const float* bg    = (const float*)d_in[11];
    const float* lng   = (const float*)d_in[12];
    const float* lnb   = (const float*)d_in[13];
    const float* glob  = (const float*)d_in[14];
    const float* Wsp   = (const float*)d_in[15];
    const float* bsp   = (const float*)d_in[16];
    float* out = (float*)d_out;

    // Fbt (bf16 features, grouped pixel-major) lives in d_out (67.1 MB);
    // fully consumed by conv before out_kernel overwrites it.
    unsigned short* Fbt = (unsigned short*)d_out;

    // workspace (floats):
    float* masks    = (float*)d_ws;              // 1,572,864
    float* ms_rep   = masks + 1572864;           // 8*8*12*64 = 49,152
    float* mask_sum = ms_rep + 49152;            // 96
    float* zero16   = mask_sum + 96;             // 8 (16B zero stub)
    float* xs       = zero16 + 8;                // 12,288
    float* ea_g     = xs + 12288;                // 8*132*64 = 67,584
    unsigned short* Wr = (unsigned short*)(ea_g + 67584);  // 294,912 bf16

    hipMemsetAsync(ms_rep, 0, (49152 + 96 + 8) * sizeof(float), stream);

    prep_kernel<<<22656, 256, 0, stream>>>(feat, Fbt, Wrpn, Wr, seg, masks, mask_sum);
    conv_node_kernel<<<1024, 512, 0, stream>>>(Fbt, Wr, brpn, Wnode, bnode,
                                               masks, zero16, ms_rep);
    edge_kernel<<<264, 256, 0, stream>>>(ms_rep, mask_sum, We1, be1, We2, be2, ea_g);
    graph_kernel<<<8, 256, 0, stream>>>(ms_rep, mask_sum, ea_g,
                                        Wg, bg, lng, lnb, glob, Wsp, xs);
    out_kernel<<<1024, 256, 0, stream>>>(xs, masks, bsp, out);
}

// Round 11
// 468.873 us; speedup vs baseline: 1.3197x; 1.2076x over previous
//
#include <hip/hip_runtime.h>
#include <math.h>

// B=8, Cin=256, H=W=128, RC=128, NC=12, HD=64, NL=3, E=132
#define BNS_F 0.9999950000374998f

typedef short short8 __attribute__((ext_vector_type(8)));   // 8 bf16 (4 VGPRs)
typedef float f32x4 __attribute__((ext_vector_type(4)));    // MFMA C/D frag

typedef __attribute__((address_space(3))) void lds_void;
typedef const __attribute__((address_space(1))) void glb_void;

__device__ __forceinline__ unsigned short f2bf(float f) {
    unsigned u = __builtin_bit_cast(unsigned, f);
    unsigned r = (u + 0x7fffu + ((u >> 16) & 1u)) >> 16;   // RNE
    return (unsigned short)r;
}
__device__ __forceinline__ float bf2f(unsigned short h) {
    unsigned u = ((unsigned)h) << 16;
    return __builtin_bit_cast(float, u);
}

// =====================================================================
// prep: fused [convert_feat | reorg_w | masks]
//  blocks [0, 16384):        feat fp32 -> Fbt bf16 [b][ic/8][y][x][8ic]
//  blocks [16384, 16512):    W_rpn -> Wr[tap][oc][ic] bf16
//  blocks [16512, 22656):    maxpool masks + mask_sum (2 rows/block)
// =====================================================================
__global__ __launch_bounds__(256) void prep_kernel(
    const float* __restrict__ feat, unsigned short* __restrict__ Fbt,
    const float* __restrict__ Wrpn, unsigned short* __restrict__ Wr,
    const float* __restrict__ seg, float* __restrict__ masks,
    float* __restrict__ mask_sum)
{
    int bid = blockIdx.x;
    int t = threadIdx.x;

    if (bid < 16384) {
        int pxc = bid & 63;
        int icg = (bid >> 6) & 31;
        int b   = bid >> 11;
        int px  = pxc * 256 + t;
        const float* src = feat + ((size_t)(b * 256 + icg * 8)) * 16384 + px;
        unsigned v[4];
        #pragma unroll
        for (int i = 0; i < 4; ++i) {
            unsigned lo = f2bf(src[(size_t)(2 * i)     * 16384]);
            unsigned hi = f2bf(src[(size_t)(2 * i + 1) * 16384]);
            v[i] = lo | (hi << 16);
        }
        uint4 o; o.x = v[0]; o.y = v[1]; o.z = v[2]; o.w = v[3];
        *(uint4*)(Fbt + (((size_t)(b * 32 + icg) * 16384) + px) * 8) = o;
    } else if (bid < 16512) {
        int oc = bid - 16384;
        const float* src = Wrpn + ((size_t)oc * 256 + t) * 9;
        #pragma unroll
        for (int tap = 0; tap < 9; ++tap)
            Wr[((size_t)tap * 128 + oc) * 256 + t] = f2bf(src[tap]);
    } else {
        int mb = bid - 16512;                  // 0..6143
        int h = (mb & 63) * 2 + (t >> 7);
        int c = (mb >> 6) % 12;
        int b = mb / (64 * 12);
        int px = t & 127;

        const float* s = seg + ((size_t)(b * 12 + c) * 128) * 128;
        float m = -INFINITY;
        #pragma unroll
        for (int dy = -1; dy <= 1; ++dy) {
            int y = h + dy;
            if (y < 0 || y > 127) continue;
            #pragma unroll
            for (int dx = -1; dx <= 1; ++dx) {
                int x = px + dx;
                if (x < 0 || x > 127) continue;
                m = fmaxf(m, s[y * 128 + x]);
            }
        }
        float v = (m > 0.5f) ? 1.0f : 0.0f;
        masks[((size_t)(b * 12 + c) * 128 + h) * 128 + px] = v;

        float cnt = v;
        #pragma unroll
        for (int off = 1; off < 64; off <<= 1) cnt += __shfl_xor(cnt, off, 64);
        if ((t & 63) == 0) atomicAdd(&mask_sum[b * 12 + c], cnt);
    }
}

// =====================================================================
// MFMA implicit-GEMM conv + fused 1x1 + masked sums.  v9: 64-REG BUCKET.
// m69 law: waves/SIMD halves at total regs {64,128,256}. All prior
// variants sat at 65-128 (4 waves/SIMD = 16 waves/CU); dur*waves ~= const
// across R5/R6/R7 => latency-bound. This version fits the <=64 bucket:
//   wave = 16oc x 64px, acc = 4 x f32x4 = 16 regs; one-VGPR B-base with
//   16-bit ds-imm offsets; one-VGPR A lane-offset + uniform SGPR base;
//   __launch_bounds__(512,8). LDS 25.3KB (dbuf 2x12.7KB, slot-major,
//   conflict-free; 'refined' aliases dead staging bufs post-barrier).
// => 4 blocks/CU x 8 waves = 32 waves/CU (2x R6). grid 2048 = Bx128Hx2.
// =====================================================================
#define BUF_B 12672                      // 792 chunks * 16B (3 rows * 66 cols * 4 slots)
#define CHUNK_STEP (4u * 16384u * 8u)    // +32 ic = +4 icg planes, in ushorts

__global__ __launch_bounds__(512, 8) void conv_node_kernel(
    const unsigned short* __restrict__ Fbt, const unsigned short* __restrict__ Wr,
    const float* __restrict__ brpn, const float* __restrict__ Wnode,
    const float* __restrict__ bnode, const float* __restrict__ masks,
    const float* __restrict__ zero16, float* __restrict__ ms_rep)
{
    __shared__ __align__(16) unsigned char lds[25344];

    // XCD swizzle: 2048 wgs, XCD x gets blocks [x*256, x*256+256) = batch x
    int wg = blockIdx.x;
    int bid = (wg & 7) * 256 + (wg >> 3);
    int b    = bid >> 8;
    int h    = (bid >> 1) & 127;
    int px0  = (bid & 1) * 64;

    int t = threadIdx.x;
    int lane = t & 63;
    int wv = __builtin_amdgcn_readfirstlane(t >> 6);  // 0..7 wave-uniform
    int kg = lane >> 4;        // k-group 0..3 (slot)
    int ln15 = lane & 15;

    f32x4 acc[4];
    #pragma unroll
    for (int nt = 0; nt < 4; ++nt) acc[nt] = (f32x4){0.f, 0.f, 0.f, 0.f};

    const unsigned short* zp = (const unsigned short*)zero16;

    // ---- staging descriptors (2 per thread), computed ONCE ----
    // chunk c = row*264 + slot*66 + col; rounds: c=t (512), c=512+t (280)
    const unsigned short* pp0;
    const unsigned short* pp1;
    #pragma unroll
    for (int r = 0; r < 2; ++r) {
        int c = r * 512 + t;
        bool act = (c < 792);
        int row = c / 264;
        int rem = c - row * 264;
        int slot = rem / 66;
        int col = rem - slot * 66;
        int y = h - 1 + row, x = px0 + col - 1;
        bool in = act && ((unsigned)y < 128u) && ((unsigned)x < 128u);
        const unsigned short* p =
            in ? (Fbt + (((size_t)(b * 32 + slot) * 16384) + y * 128 + x) * 8) : zp;
        if (r == 0) pp0 = p; else pp1 = p;
    }

    auto stage = [&](int bsel) {
        unsigned lo0 = (unsigned)bsel * BUF_B + (unsigned)(wv * 64) * 16;
        __builtin_amdgcn_global_load_lds((glb_void*)pp0,
            (lds_void*)(lds + lo0), 16, 0, 0);
        pp0 += (pp0 == zp) ? 0u : CHUNK_STEP;
        if (512 + t < 792) {
            unsigned lo1 = (unsigned)bsel * BUF_B + (unsigned)(512 + wv * 64) * 16;
            __builtin_amdgcn_global_load_lds((glb_void*)pp1,
                (lds_void*)(lds + lo1), 16, 0, 0);
        }
        pp1 += (pp1 == zp) ? 0u : CHUNK_STEP;
    };

    // per-lane invariant addresses
    unsigned vb = (unsigned)(kg * 66 + ln15) * 16;       // B lane base (bytes)
    unsigned laneA = (unsigned)(ln15 * 256 + kg * 8);    // A lane offset (ushorts)

    stage(0);
    __syncthreads();

    for (int s = 0; s < 8; ++s) {
        const unsigned short* wpu = Wr + (size_t)(wv * 16) * 256 + s * 32 + laneA;
        unsigned bb = (unsigned)(s & 1) * BUF_B + vb;

        #pragma unroll
        for (int dy = 0; dy < 3; ++dy) {
            #pragma unroll
            for (int dxi = 0; dxi < 3; ++dxi) {
                int tap = dy * 3 + dxi;
                short8 a = *(const short8*)(wpu + (size_t)tap * 32768);
                #pragma unroll
                for (int nt = 0; nt < 4; ++nt) {
                    short8 bf = *(const short8*)
                        (lds + bb + (unsigned)((dy * 264 + dxi) * 16 + nt * 256));
                    acc[nt] = __builtin_amdgcn_mfma_f32_16x16x32_bf16(
                        a, bf, acc[nt], 0, 0, 0);
                }
            }
        }

        if (s < 7) stage((s + 1) & 1);   // R6 proven order: stage after compute
        __syncthreads();
    }

    // ---- epilogue: refined (bias/BNS/ReLU) -> LDS bf16 [128 oc][stride 66] ----
    // (aliases staging buffers; safe: post-barrier, staging dead)
    unsigned short* refined = (unsigned short*)lds;
    #pragma unroll
    for (int nt = 0; nt < 4; ++nt) {
        #pragma unroll
        for (int r = 0; r < 4; ++r) {
            int oc = wv * 16 + kg * 4 + r;        // D: row=(lane>>4)*4+r
            int px = nt * 16 + ln15;
            float v = fmaxf((acc[nt][r] + brpn[oc]) * BNS_F, 0.f);
            refined[oc * 66 + px] = f2bf(v);
        }
    }
    __syncthreads();

    // ---- phase 2: z = relu((W_node @ refined + b)*BNS); wave -> 8 dims ----
    float z[8];
    #pragma unroll
    for (int j = 0; j < 8; ++j) z[j] = 0.f;
    const float* wn = Wnode + (size_t)(wv * 8) * 128;
    for (int k = 0; k < 128; ++k) {
        float rv = bf2f(refined[k * 66 + lane]);
        #pragma unroll
        for (int j = 0; j < 8; ++j)
            z[j] = fmaf(wn[j * 128 + k], rv, z[j]);
    }
    #pragma unroll
    for (int j = 0; j < 8; ++j)
        z[j] = fmaxf((z[j] + bnode[wv * 8 + j]) * BNS_F, 0.f);

    // ---- masked accumulation into replica rep = bid&7 ----
    int rep = bid & 7;
    const float* mrow = masks + ((size_t)b * 12 * 128 + h) * 128 + px0;
    float* msb = ms_rep + ((size_t)(rep * 8 + b) * 12) * 64 + wv * 8;
    for (int c = 0; c < 12; ++c) {
        float m = mrow[(size_t)c * 16384 + lane];
        #pragma unroll
        for (int j = 0; j < 8; ++j) {
            float v = z[j] * m;
            #pragma unroll
            for (int off2 = 1; off2 < 64; off2 <<= 1) v += __shfl_xor(v, off2, 64);
            if (lane == j) atomicAdd(&msb[c * 64 + j], v);
        }
    }
}

// =====================================================================
// edge MLP: 264 blocks = 8 b x 33 edge-groups; wave = one edge
// =====================================================================
__global__ __launch_bounds__(256) void edge_kernel(
    const float* __restrict__ ms_rep, const float* __restrict__ mask_sum,
    const float* __restrict__ We1, const float* __restrict__ be1,
    const float* __restrict__ We2, const float* __restrict__ be2,
    float* __restrict__ ea_g)
{
    int gb = blockIdx.x;
    int b = gb / 33, eg = gb % 33;
    int wv = threadIdx.x >> 6, d = threadIdx.x & 63;
    int e = eg * 4 + wv;                    // 0..131
    int src = e / 11, jj = e % 11;
    int dst = jj + (jj >= src ? 1 : 0);

    float mssrc = 0.f, msdst = 0.f;
    #pragma unroll
    for (int rep = 0; rep < 8; ++rep) {
        mssrc += ms_rep[((size_t)(rep * 8 + b) * 12 + src) * 64 + d];
        msdst += ms_rep[((size_t)(rep * 8 + b) * 12 + dst) * 64 + d];
    }
    float cs = mask_sum[b * 12 + src], cd = mask_sum[b * 12 + dst];
    float nsrc = mssrc / (cs + 1e-6f);
    float ndst = msdst / (cd + 1e-6f);

    float hv = be1[d];
    for (int k = 0; k < 64; ++k) hv = fmaf(__shfl(nsrc, k, 64), We1[k * 64 + d], hv);
    for (int k = 0; k < 64; ++k) hv = fmaf(__shfl(ndst, k, 64), We1[(64 + k) * 64 + d], hv);
    hv = fmaxf(hv, 0.f);
    float av = be2[d];
    for (int k = 0; k < 64; ++k) av = fmaf(__shfl(hv, k, 64), We2[k * 64 + d], av);

    float valid = ((cs > 0.f) ? 1.f : 0.f) * ((cd > 0.f) ? 1.f : 0.f);
    ea_g[((size_t)b * 132 + e) * 64 + d] = av * valid;
}

// =====================================================================
// graph: node_feats -> 3-layer GNN -> xs = x_final @ W_sp  (8 blocks)
// =====================================================================
__global__ __launch_bounds__(256) void graph_kernel(
    const float* __restrict__ ms_rep, const float* __restrict__ mask_sum,
    const float* __restrict__ ea_g,
    const float* __restrict__ Wg, const float* __restrict__ bg,
    const float* __restrict__ lng, const float* __restrict__ lnb,
    const float* __restrict__ glob, const float* __restrict__ Wsp,
    float* __restrict__ xs_out)
{
    __shared__ float nf[12 * 64];
    __shared__ float x [12 * 64];
    __shared__ float xw[12 * 64];
    __shared__ float ea[132 * 64];
    __shared__ float presence[12];

    int b = blockIdx.x;
    int t = threadIdx.x;

    for (int i = t; i < 768; i += 256) {
        int c = i >> 6, d = i & 63;
        float ms = 0.f;
        #pragma unroll
        for (int rep = 0; rep < 8; ++rep)
            ms += ms_rep[((size_t)(rep * 8 + b) * 12 + c) * 64 + d];
        nf[i] = ms / (mask_sum[b * 12 + c] + 1e-6f);
    }
    for (int i = t; i < 132 * 64; i += 256) ea[i] = ea_g[(size_t)b * 8448 + i];
    __syncthreads();

    for (int i = t; i < 768; i += 256) {
        int c = i >> 6;
        float v = nf[i];
        #pragma unroll
        for (int off = 1; off < 64; off <<= 1) v += __shfl_xor(v, off, 64);
        if ((i & 63) == 0) presence[c] = (v != 0.f) ? 1.f : 0.f;
        x[i] = nf[i];
    }
    __syncthreads();

    for (int l = 0; l < 3; ++l) {
        const float* wg = Wg + l * 4096;
        for (int i = t; i < 768; i += 256) {
            int c = i >> 6, d = i & 63;
            float v = 0.f;
            for (int k = 0; k < 64; ++k) v = fmaf(x[c * 64 + k], wg[k * 64 + d], v);
            xw[i] = v;
        }
        __syncthreads();
        for (int i = t; i < 768; i += 256) {
            int j = i >> 6, d = i & 63;
            float agg = bg[l * 64 + d];
            #pragma unroll
            for (int src2 = 0; src2 < 12; ++src2) {
                if (src2 == j) continue;
                int jj2 = j - (j > src2 ? 1 : 0);
                int e = src2 * 11 + jj2;
                agg = fmaf(xw[src2 * 64 + d], ea[e * 64 + d], agg);
            }
            float xr = fmaxf(agg, 0.f);
            float s = xr;
            #pragma unroll
            for (int off = 1; off < 64; off <<= 1) s += __shfl_xor(s, off, 64);
            float mu = s * (1.f / 64.f);
            float df = xr - mu;
            float s2 = df * df;
            #pragma unroll
            for (int off = 1; off < 64; off <<= 1) s2 += __shfl_xor(s2, off, 64);
            float var = s2 * (1.f / 64.f);
            float normed = df * (1.0f / sqrtf(var + 1e-5f)) * lng[l * 64 + d]
                           + lnb[l * 64 + d];
            nf[i] = (l > 0) ? (normed + x[i]) : normed;
        }
        __syncthreads();
        for (int i = t; i < 768; i += 256) x[i] = nf[i];
        __syncthreads();
    }

    for (int i = t; i < 768; i += 256) {
        int c = i >> 6;
        float p = presence[c];
        x[i] = x[i] * p + glob[c * 64 + (i & 63)] * (1.f - p);
    }
    __syncthreads();

    for (int i = t; i < 12 * 128; i += 256) {
        int c = i >> 7, o = i & 127;
        float v = 0.f;
        for (int k = 0; k < 64; ++k) v = fmaf(x[c * 64 + k], Wsp[k * 128 + o], v);
        xs_out[b * 1536 + i] = v;
    }
}

// =====================================================================
// out[b,o,h,w] = relu((sum_c xs[b,c,o]*mask[b,c,h,w] + b_sp[o])*BNS)
// =====================================================================
__global__ __launch_bounds__(256) void out_kernel(
    const float* __restrict__ xs, const float* __restrict__ masks,
    const float* __restrict__ bsp, float* __restrict__ out)
{
    __shared__ float xsl[12 * 128];
    __shared__ float ml[12 * 128];
    int bid = blockIdx.x;
    int h = bid & 127;
    int b = bid >> 7;
    int t = threadIdx.x;

    for (int i = t; i < 1536; i += 256) xsl[i] = xs[b * 1536 + i];
    for (int i = t; i < 1536; i += 256) {
        int c = i >> 7, px = i & 127;
        ml[i] = masks[((size_t)(b * 12 + c) * 128 + h) * 128 + px];
    }
    __syncthreads();

    int px = t & 127;
    int og = t >> 7;
    float m[12];
    #pragma unroll
    for (int c = 0; c < 12; ++c) m[c] = ml[c * 128 + px];

    float* ob = out + ((size_t)b * 128 * 128 + h) * 128 + px;
    for (int i = 0; i < 64; ++i) {
        int o = og * 64 + i;
        float s = 0.f;
        #pragma unroll
        for (int c = 0; c < 12; ++c) s = fmaf(xsl[c * 128 + o], m[c], s);
        ob[(size_t)o * 16384] = fmaxf((s + bsp[o]) * BNS_F, 0.f);
    }
}

// =====================================================================
extern "C" void kernel_launch(void* const* d_in, const int* in_sizes, int n_in,
                              void* d_out, int out_size, void* d_ws, size_t ws_size,
                              hipStream_t stream)
{
    const float* feat  = (const float*)d_in[0];
    const float* seg   = (const float*)d_in[1];
    const float* Wrpn  = (const float*)d_in[2];
    const float* brpn  = (const float*)d_in[3];
    const float* Wnode = (const float*)d_in[4];
    const float* bnode = (const float*)d_in[5];
    const float* We1   = (const float*)d_in[6];
    const float* be1   = (const float*)d_in[7];
    const float* We2   = (const float*)d_in[8];
    const float* be2   = (const float*)d_in[9];
    const float* Wg    = (const float*)d_in[10];
    const float* bg    = (const float*)d_in[11];
    const float* lng   = (const float*)d_in[12];
    const float* lnb   = (const float*)d_in[13];
    const float* glob  = (const float*)d_in[14];
    const float* Wsp   = (const float*)d_in[15];
    const float* bsp   = (const float*)d_in[16];
    float* out = (float*)d_out;

    // Fbt (bf16 features, grouped pixel-major) lives in d_out (67.1 MB);
    // fully consumed by conv before out_kernel overwrites it.
    unsigned short* Fbt = (unsigned short*)d_out;

    // workspace (floats):
    float* masks    = (float*)d_ws;              // 1,572,864
    float* ms_rep   = masks + 1572864;           // 8*8*12*64 = 49,152
    float* mask_sum = ms_rep + 49152;            // 96
    float* zero16   = mask_sum + 96;             // 8 (16B zero stub)
    float* xs       = zero16 + 8;                // 12,288
    float* ea_g     = xs + 12288;                // 8*132*64 = 67,584
    unsigned short* Wr = (unsigned short*)(ea_g + 67584);  // 294,912 bf16

    hipMemsetAsync(ms_rep, 0, (49152 + 96 + 8) * sizeof(float), stream);

    prep_kernel<<<22656, 256, 0, stream>>>(feat, Fbt, Wrpn, Wr, seg, masks, mask_sum);
    conv_node_kernel<<<2048, 512, 0, stream>>>(Fbt, Wr, brpn, Wnode, bnode,
                                               masks, zero16, ms_rep);
    edge_kernel<<<264, 256, 0, stream>>>(ms_rep, mask_sum, We1, be1, We2, be2, ea_g);
    graph_kernel<<<8, 256, 0, stream>>>(ms_rep, mask_sum, ea_g,
                                        Wg, bg, lng, lnb, glob, Wsp, xs);
    out_kernel<<<1024, 256, 0, stream>>>(xs, masks, bsp, out);
}